// Round 1
// baseline (65.796 us; speedup 1.0000x reference)
//
#include <hip/hip_runtime.h>

// SoftNCutLoss: image [4,3,256,256] f32, enc [4,4,256,256] f32 -> scalar f32.
// dsq <= RADIUS(=5) mask leaves only 21 active offsets (|dy|,|dx| <= 2).
// R1: LDS halo tiles, __expf, block-slot partials (68.8 us).
// R2: fused threadfence-reduction REGRESSED (86 us) — reverted.
// R3: 4 px/thread 1x4 strip, 32x32 tile, grid=256 (64.8 us). Counters show
//     1 wave/SIMD (4 waves/CU) — latency-bound, ~1 us of issue cycles
//     stretched to ~20 us by unhidden LDS/global/barrier latency.
// R4: occupancy fix. 32x16 tiles, 256 thr, 2 px/thread VERTICAL pairs
//     (26-read window union = 13 reads/px), grid=512 -> 2 blocks/CU =
//     8 waves/CU (2/SIMD) + cross-block barrier overlap. Center tap
//     special-cased (wg==1, no exp). Predict snc_main ~halves.

#define HALO   2
#define TW     36                         // 32 + 2*HALO (tile width + halo)
#define TH     20                         // 16 + 2*HALO (tile height + halo)
#define TP     37                         // odd stride -> <=2-way banks (free)

// dw[dr+2][dc+2] = exp(-(dr^2+dc^2)/16), masked dsq<=5 (masked entries unused)
__device__ __constant__ float c_dw5[5][5] = {
    {0.0f,        0.73161563f, 0.77880078f, 0.73161563f, 0.0f       },
    {0.73161563f, 0.88249690f, 0.93941306f, 0.88249690f, 0.73161563f},
    {0.77880078f, 0.93941306f, 1.00000000f, 0.93941306f, 0.77880078f},
    {0.73161563f, 0.88249690f, 0.93941306f, 0.88249690f, 0.73161563f},
    {0.0f,        0.73161563f, 0.77880078f, 0.73161563f, 0.0f       }};

// d_ws: part[512][8] floats. Block g writes part[g][0..7] = {num0..3, den0..3}.

__global__ __launch_bounds__(256, 2) void snc_main(const float* __restrict__ img,
                                                   const float* __restrict__ enc,
                                                   float* __restrict__ part) {
    __shared__ float  sGray[TH * TP];
    __shared__ float4 sEnc [TH * TP];
    __shared__ float  red[4][8];

    // grid: 4 batches * (16 row-tiles * 8 col-tiles) = 512 blocks
    const int b    = blockIdx.x >> 7;
    const int tile = blockIdx.x & 127;
    const int ph   = (tile >> 3) << 4;           // row-tile * 16
    const int pw   = (tile & 7) << 5;            // col-tile * 32

    const float* __restrict__ imgb = img + b * 3 * 65536;
    const float* __restrict__ encb = enc + b * 4 * 65536;

    const int tid = threadIdx.x;

    // ---- stage 36x20 halo: gray (mean of 3 ch) + enc float4 ----
    for (int i = tid; i < TW * TH; i += 256) {
        const int gy = i / TW;
        const int gx = i - gy * TW;
        const int hh = ph + gy - HALO;
        const int ww = pw + gx - HALO;
        const bool inb = ((unsigned)hh < 256u) && ((unsigned)ww < 256u);
        float g = 0.0f;
        float4 e = make_float4(0.0f, 0.0f, 0.0f, 0.0f);
        if (inb) {
            const int o = (hh << 8) | ww;
            g = (imgb[o] + imgb[65536 + o] + imgb[131072 + o]) * (1.0f / 3.0f);
            e.x = encb[o];
            e.y = encb[65536 + o];
            e.z = encb[131072 + o];
            e.w = encb[196608 + o];
        }
        sGray[gy * TP + gx] = g;
        sEnc [gy * TP + gx] = e;
    }
    __syncthreads();

    // ---- 2 pixels per thread: vertical pair (y0, y0+1) ----
    const int x  = tid & 31;                     // col 0..31
    const int y0 = (tid >> 5) << 1;              // 0,2,...,14
    const int cb = (y0 + HALO) * TP + (x + HALO);

    const float  cgA = sGray[cb];
    const float  cgB = sGray[cb + TP];
    const float4 ceA = sEnc [cb];
    const float4 ceB = sEnc [cb + TP];

    float wsA = 0.0f, a0 = 0.0f, a1 = 0.0f, a2 = 0.0f, a3 = 0.0f;
    float wsB = 0.0f, b0 = 0.0f, b1 = 0.0f, b2 = 0.0f, b3 = 0.0f;

#pragma unroll
    for (int rr = -2; rr <= 3; ++rr) {           // union rows for the pair
        const int lo = (rr == -2 || rr == 3) ? -1 : -2;
        const int base = cb + rr * TP;
#pragma unroll
        for (int dc = lo; dc <= -lo; ++dc) {     // union cols this row
            const float  g = sGray[base + dc];
            const float4 e = sEnc [base + dc];
            // pixel A: dr = rr  (all guards fold at compile time)
            if (rr >= -2 && rr <= 2 && rr * rr + dc * dc <= 5) {
                if (rr == 0 && dc == 0) {        // center: wg == 1 exactly
                    wsA += 1.0f;
                    a0 += e.x; a1 += e.y; a2 += e.z; a3 += e.w;
                } else {
                    const float d  = g - cgA;
                    const float wg = __expf(d * d * -0.01f) * c_dw5[rr + 2][dc + 2];
                    wsA += wg;
                    a0 += wg * e.x; a1 += wg * e.y; a2 += wg * e.z; a3 += wg * e.w;
                }
            }
            // pixel B: dr = rr - 1
            if ((rr - 1) >= -2 && (rr - 1) <= 2 && (rr - 1) * (rr - 1) + dc * dc <= 5) {
                if ((rr - 1) == 0 && dc == 0) {  // center
                    wsB += 1.0f;
                    b0 += e.x; b1 += e.y; b2 += e.z; b3 += e.w;
                } else {
                    const float d  = g - cgB;
                    const float wg = __expf(d * d * -0.01f) * c_dw5[rr + 1][dc + 2];
                    wsB += wg;
                    b0 += wg * e.x; b1 += wg * e.y; b2 += wg * e.z; b3 += wg * e.w;
                }
            }
        }
    }

    float v[8];
    v[0] = ceA.x * a0 + ceB.x * b0;
    v[1] = ceA.y * a1 + ceB.y * b1;
    v[2] = ceA.z * a2 + ceB.z * b2;
    v[3] = ceA.w * a3 + ceB.w * b3;
    v[4] = ceA.x * wsA + ceB.x * wsB;
    v[5] = ceA.y * wsA + ceB.y * wsB;
    v[6] = ceA.z * wsA + ceB.z * wsB;
    v[7] = ceA.w * wsA + ceB.w * wsB;

    // wave64 shuffle reduce
#pragma unroll
    for (int off = 32; off; off >>= 1) {
#pragma unroll
        for (int j = 0; j < 8; ++j) v[j] += __shfl_down(v[j], off);
    }

    const int wave = tid >> 6;
    const int lane = tid & 63;
    if (lane == 0) {
#pragma unroll
        for (int j = 0; j < 8; ++j) red[wave][j] = v[j];
    }
    __syncthreads();

    if (tid < 8) {
        part[blockIdx.x * 8 + tid] =
            red[0][tid] + red[1][tid] + red[2][tid] + red[3][tid];
    }
}

__global__ __launch_bounds__(256) void snc_final(const float* __restrict__ part,
                                                 float* __restrict__ out) {
    const int t    = threadIdx.x;
    const int b    = t >> 6;                     // one wave per batch (128 blocks each)
    const int lane = t & 63;

    const float4* p0 = (const float4*)(part + (size_t)(b * 128 + lane) * 8);
    const float4* p1 = (const float4*)(part + (size_t)(b * 128 + 64 + lane) * 8);
    const float4 a0 = p0[0];
    const float4 a1 = p0[1];
    const float4 c0 = p1[0];
    const float4 c1 = p1[1];
    float v[8] = {a0.x + c0.x, a0.y + c0.y, a0.z + c0.z, a0.w + c0.w,
                  a1.x + c1.x, a1.y + c1.y, a1.z + c1.z, a1.w + c1.w};

#pragma unroll
    for (int off = 32; off; off >>= 1) {
#pragma unroll
        for (int j = 0; j < 8; ++j) v[j] += __shfl_down(v[j], off);
    }

    __shared__ float res[4];
    if (lane == 0) {
        float s = 0.0f;
#pragma unroll
        for (int k = 0; k < 4; ++k) s += v[k] / (v[4 + k] + 1e-8f);
        res[b] = 4.0f - s;
    }
    __syncthreads();
    if (t == 0) out[0] = (res[0] + res[1] + res[2] + res[3]) * 0.25f;
}

extern "C" void kernel_launch(void* const* d_in, const int* in_sizes, int n_in,
                              void* d_out, int out_size, void* d_ws, size_t ws_size,
                              hipStream_t stream) {
    const float* img = (const float*)d_in[0];   // [4,3,256,256]
    const float* enc = (const float*)d_in[1];   // [4,4,256,256]
    float* out  = (float*)d_out;                // scalar
    float* part = (float*)d_ws;                 // [512][8] floats

    snc_main<<<dim3(512), dim3(256), 0, stream>>>(img, enc, part);
    snc_final<<<dim3(1), dim3(256), 0, stream>>>(part, out);
}

// Round 2
// 65.207 us; speedup vs baseline: 1.0090x; 1.0090x over previous
//
#include <hip/hip_runtime.h>

// SoftNCutLoss: image [4,3,256,256] f32, enc [4,4,256,256] f32 -> scalar f32.
// dsq <= RADIUS(=5) mask leaves only 21 active offsets (|dy|,|dx| <= 2).
// R1: LDS halo tiles, __expf, block-slot partials (68.8 us).
// R2: fused threadfence-reduction REGRESSED (86 us) — reverted.
// R3: 4 px/thread 1x4 strip, 32x32 tile, grid=256 (64.8 us).
// R4: 32x16 tiles, 2 px/thread vertical pair, grid=512, 2 blk/CU (65.8 us,
//     NEUTRAL). Occupancy was not the limit.
// R5: staging MLP fix. The 268 MB workspace fill evicts L2+LLC every iter,
//     so all staging loads are HBM cold misses (~900 cyc). Scalar 4 B loads
//     gave <1 KB in flight/CU (need ~9 KB for 10 B/cyc/CU) -> staging was
//     ~15 us latency-bound. Now: aligned float4 staging, 40-float rows
//     [pw-4,pw+36) so chunks are 16 B aligned and all-or-nothing in-bounds;
//     7x global_load_dwordx4 per staging thread (112 B in flight/thread,
//     ~45 KB/CU) -> staging BW-bound ~2 us. Enc transposed in-register to
//     per-pixel float4 AoS. Predict snc_main ~17 -> ~5 us, total ~51.

#define HALO  2
#define TH    20            // staged rows: 16 + 2*HALO
#define NCH   10            // float4 chunks per row (40 floats)
#define GP    44            // sGray row stride (floats): 16B-aligned rows,
                            //   half-wave (2-row) offset 88 % 32 = 24 banks
#define EP    41            // sEnc row stride (float4): 2-row offset 328
                            //   dwords % 32 = 8 banks; odd -> no aliasing

// dw[dr+2][dc+2] = exp(-(dr^2+dc^2)/16), masked dsq<=5 (masked entries unused)
__device__ __constant__ float c_dw5[5][5] = {
    {0.0f,        0.73161563f, 0.77880078f, 0.73161563f, 0.0f       },
    {0.73161563f, 0.88249690f, 0.93941306f, 0.88249690f, 0.73161563f},
    {0.77880078f, 0.93941306f, 1.00000000f, 0.93941306f, 0.77880078f},
    {0.73161563f, 0.88249690f, 0.93941306f, 0.88249690f, 0.73161563f},
    {0.0f,        0.73161563f, 0.77880078f, 0.73161563f, 0.0f       }};

// d_ws: part[512][8] floats. Block g writes part[g][0..7] = {num0..3, den0..3}.

__global__ __launch_bounds__(256, 2) void snc_main(const float* __restrict__ img,
                                                   const float* __restrict__ enc,
                                                   float* __restrict__ part) {
    __shared__ float  sGray[TH * GP];
    __shared__ float4 sEnc [TH * EP];
    __shared__ float  red[4][8];

    // grid: 4 batches * (16 row-tiles * 8 col-tiles) = 512 blocks
    const int b    = blockIdx.x >> 7;
    const int tile = blockIdx.x & 127;
    const int ph   = (tile >> 3) << 4;           // row-tile * 16
    const int pw   = (tile & 7) << 5;            // col-tile * 32

    const float* __restrict__ imgb = img + b * 3 * 65536;
    const float* __restrict__ encb = enc + b * 4 * 65536;

    const int tid = threadIdx.x;

    // ---- stage 20 rows x 40 cols halo with aligned float4 loads ----
    // Chunk cols cc = pw-4+4*j are 4-aligned; W=256 -> chunk is fully
    // in-bounds iff (unsigned)cc < 256. OOB chunks/rows stage zeros
    // (= reference zero padding).
    if (tid < TH * NCH) {
        const int gy  = tid / NCH;               // 0..19
        const int gx4 = tid - gy * NCH;          // 0..9
        const int hh  = ph + gy - HALO;
        const int cc  = pw - 4 + (gx4 << 2);
        float4 g4 = make_float4(0.0f, 0.0f, 0.0f, 0.0f);
        float4 e0 = g4, e1 = g4, e2 = g4, e3 = g4;
        if (((unsigned)hh < 256u) && ((unsigned)cc < 256u)) {
            const int o = (hh << 8) | cc;        // 16B-aligned offset
            const float4 i0 = *(const float4*)(imgb + o);
            const float4 i1 = *(const float4*)(imgb + 65536 + o);
            const float4 i2 = *(const float4*)(imgb + 131072 + o);
            e0 = *(const float4*)(encb + o);
            e1 = *(const float4*)(encb + 65536 + o);
            e2 = *(const float4*)(encb + 131072 + o);
            e3 = *(const float4*)(encb + 196608 + o);
            const float s = 1.0f / 3.0f;
            g4.x = (i0.x + i1.x + i2.x) * s;
            g4.y = (i0.y + i1.y + i2.y) * s;
            g4.z = (i0.z + i1.z + i2.z) * s;
            g4.w = (i0.w + i1.w + i2.w) * s;
        }
        *(float4*)&sGray[gy * GP + (gx4 << 2)] = g4;   // 16B aligned (GP=44)
        const int eb = gy * EP + (gx4 << 2);
        sEnc[eb + 0] = make_float4(e0.x, e1.x, e2.x, e3.x);
        sEnc[eb + 1] = make_float4(e0.y, e1.y, e2.y, e3.y);
        sEnc[eb + 2] = make_float4(e0.z, e1.z, e2.z, e3.z);
        sEnc[eb + 3] = make_float4(e0.w, e1.w, e2.w, e3.w);
    }
    __syncthreads();

    // ---- 2 pixels per thread: vertical pair (y0, y0+1) ----
    // Pixel x lives at staged col x+4 (staged cols start at pw-4).
    const int x   = tid & 31;                    // col 0..31
    const int y0  = (tid >> 5) << 1;             // 0,2,...,14
    const int cbG = (y0 + HALO) * GP + (x + 4);
    const int cbE = (y0 + HALO) * EP + (x + 4);

    const float  cgA = sGray[cbG];
    const float  cgB = sGray[cbG + GP];
    const float4 ceA = sEnc [cbE];
    const float4 ceB = sEnc [cbE + EP];

    float wsA = 0.0f, a0 = 0.0f, a1 = 0.0f, a2 = 0.0f, a3 = 0.0f;
    float wsB = 0.0f, b0 = 0.0f, b1 = 0.0f, b2 = 0.0f, b3 = 0.0f;

#pragma unroll
    for (int rr = -2; rr <= 3; ++rr) {           // union rows for the pair
        const int lo = (rr == -2 || rr == 3) ? -1 : -2;
        const int baseG = cbG + rr * GP;
        const int baseE = cbE + rr * EP;
#pragma unroll
        for (int dc = lo; dc <= -lo; ++dc) {     // union cols this row
            const float  g = sGray[baseG + dc];
            const float4 e = sEnc [baseE + dc];
            // pixel A: dr = rr  (all guards fold at compile time)
            if (rr >= -2 && rr <= 2 && rr * rr + dc * dc <= 5) {
                if (rr == 0 && dc == 0) {        // center: wg == 1 exactly
                    wsA += 1.0f;
                    a0 += e.x; a1 += e.y; a2 += e.z; a3 += e.w;
                } else {
                    const float d  = g - cgA;
                    const float wg = __expf(d * d * -0.01f) * c_dw5[rr + 2][dc + 2];
                    wsA += wg;
                    a0 += wg * e.x; a1 += wg * e.y; a2 += wg * e.z; a3 += wg * e.w;
                }
            }
            // pixel B: dr = rr - 1
            if ((rr - 1) >= -2 && (rr - 1) <= 2 && (rr - 1) * (rr - 1) + dc * dc <= 5) {
                if ((rr - 1) == 0 && dc == 0) {  // center
                    wsB += 1.0f;
                    b0 += e.x; b1 += e.y; b2 += e.z; b3 += e.w;
                } else {
                    const float d  = g - cgB;
                    const float wg = __expf(d * d * -0.01f) * c_dw5[rr + 1][dc + 2];
                    wsB += wg;
                    b0 += wg * e.x; b1 += wg * e.y; b2 += wg * e.z; b3 += wg * e.w;
                }
            }
        }
    }

    float v[8];
    v[0] = ceA.x * a0 + ceB.x * b0;
    v[1] = ceA.y * a1 + ceB.y * b1;
    v[2] = ceA.z * a2 + ceB.z * b2;
    v[3] = ceA.w * a3 + ceB.w * b3;
    v[4] = ceA.x * wsA + ceB.x * wsB;
    v[5] = ceA.y * wsA + ceB.y * wsB;
    v[6] = ceA.z * wsA + ceB.z * wsB;
    v[7] = ceA.w * wsA + ceB.w * wsB;

    // wave64 shuffle reduce
#pragma unroll
    for (int off = 32; off; off >>= 1) {
#pragma unroll
        for (int j = 0; j < 8; ++j) v[j] += __shfl_down(v[j], off);
    }

    const int wave = tid >> 6;
    const int lane = tid & 63;
    if (lane == 0) {
#pragma unroll
        for (int j = 0; j < 8; ++j) red[wave][j] = v[j];
    }
    __syncthreads();

    if (tid < 8) {
        part[blockIdx.x * 8 + tid] =
            red[0][tid] + red[1][tid] + red[2][tid] + red[3][tid];
    }
}

__global__ __launch_bounds__(256) void snc_final(const float* __restrict__ part,
                                                 float* __restrict__ out) {
    const int t    = threadIdx.x;
    const int b    = t >> 6;                     // one wave per batch (128 blocks each)
    const int lane = t & 63;

    const float4* p0 = (const float4*)(part + (size_t)(b * 128 + lane) * 8);
    const float4* p1 = (const float4*)(part + (size_t)(b * 128 + 64 + lane) * 8);
    const float4 a0 = p0[0];
    const float4 a1 = p0[1];
    const float4 c0 = p1[0];
    const float4 c1 = p1[1];
    float v[8] = {a0.x + c0.x, a0.y + c0.y, a0.z + c0.z, a0.w + c0.w,
                  a1.x + c1.x, a1.y + c1.y, a1.z + c1.z, a1.w + c1.w};

#pragma unroll
    for (int off = 32; off; off >>= 1) {
#pragma unroll
        for (int j = 0; j < 8; ++j) v[j] += __shfl_down(v[j], off);
    }

    __shared__ float res[4];
    if (lane == 0) {
        float s = 0.0f;
#pragma unroll
        for (int k = 0; k < 4; ++k) s += v[k] / (v[4 + k] + 1e-8f);
        res[b] = 4.0f - s;
    }
    __syncthreads();
    if (t == 0) out[0] = (res[0] + res[1] + res[2] + res[3]) * 0.25f;
}

extern "C" void kernel_launch(void* const* d_in, const int* in_sizes, int n_in,
                              void* d_out, int out_size, void* d_ws, size_t ws_size,
                              hipStream_t stream) {
    const float* img = (const float*)d_in[0];   // [4,3,256,256]
    const float* enc = (const float*)d_in[1];   // [4,4,256,256]
    float* out  = (float*)d_out;                // scalar
    float* part = (float*)d_ws;                 // [512][8] floats

    snc_main<<<dim3(512), dim3(256), 0, stream>>>(img, enc, part);
    snc_final<<<dim3(1), dim3(256), 0, stream>>>(part, out);
}